// Round 14
// baseline (324.177 us; speedup 1.0000x reference)
//
#include <hip/hip_runtime.h>
#include <hip/hip_bf16.h>
#include <hip/hip_fp16.h>

typedef short bshort8 __attribute__((ext_vector_type(8)));
typedef float f32x4 __attribute__((ext_vector_type(4)));
typedef unsigned short ushort8v __attribute__((ext_vector_type(8)));

__device__ __forceinline__ int clampi(int v, int lo, int hi) {
    return v < lo ? lo : (v > hi ? hi : v);
}
__device__ __forceinline__ ushort f2bf(float f) {           // RNE f32 -> bf16 bits
    uint u = __float_as_uint(f);
    return (ushort)((u + 0x7FFFu + ((u >> 16) & 1u)) >> 16);
}
__device__ __forceinline__ float bf2f(ushort b) { return __uint_as_float(((uint)b) << 16); }

__device__ __forceinline__ float dot8(float4 qA, float4 qB, ushort8v k8) {
    return qA.x * bf2f(k8[0]) + qA.y * bf2f(k8[1]) + qA.z * bf2f(k8[2]) + qA.w * bf2f(k8[3])
         + qB.x * bf2f(k8[4]) + qB.y * bf2f(k8[5]) + qB.z * bf2f(k8[6]) + qB.w * bf2f(k8[7]);
}

// Edge record: src in bits [31:15] (17b), ea as fp16>>1 in bits [14:0].
__device__ __forceinline__ uint pack_edge(int src, float ea) {
    ushort h = __half_as_ushort(__float2half(ea));
    return ((uint)src << 15) | ((uint)(h >> 1) & 0x7FFFu);
}
__device__ __forceinline__ int rec_src(uint r) { return (int)(r >> 15); }
__device__ __forceinline__ float rec_ea(uint r) {
    return __half2float(__ushort_as_half((ushort)((r & 0x7FFFu) << 1)));
}

// ---------------------------------------------------------------------------
// Pack both layers' weights into per-lane MFMA B-fragments (blocks 0..15);
// zero histogram counters + degree bins (blocks >= 16).
// ---------------------------------------------------------------------------
__global__ void pack_and_zero(const float* __restrict__ Wq1, const float* __restrict__ Wk1,
                              const float* __restrict__ Wv1, const float* __restrict__ Ws1,
                              const float* __restrict__ Wq2, const float* __restrict__ Wk2,
                              const float* __restrict__ Wv2, const float* __restrict__ Ws2,
                              ushort* __restrict__ Bp1, ushort* __restrict__ Bp2,
                              int* __restrict__ count, int* __restrict__ dcount, int n) {
    if (blockIdx.x >= 16) {
        int j = (blockIdx.x - 16) * 256 + threadIdx.x;
        if (j < n) count[j] = 0;
        if (blockIdx.x == 16 && threadIdx.x < 64) dcount[threadIdx.x] = 0;
        return;
    }
    int tid = blockIdx.x * 256 + threadIdx.x;          // 0..4095
    int layer = tid >> 11;
    int t2 = tid & 2047;
    int lane = t2 & 63;
    int th = t2 >> 6;                  // t*2 + h
    int h = th & 1, t = th >> 1;
    const float* W = layer ? ((t < 4) ? Wq2 : (t < 8) ? Wk2 : (t < 12) ? Wv2 : Ws2)
                           : ((t < 4) ? Wq1 : (t < 8) ? Wk1 : (t < 12) ? Wv1 : Ws1);
    ushort* Bp = layer ? Bp2 : Bp1;
    int col = ((t & 3) << 4) + (lane & 15);
    int g = lane >> 4;
    #pragma unroll
    for (int i = 0; i < 8; ++i) {
        int k = 32 * h + 16 * (i >> 2) + 4 * g + (i & 3);
        Bp[t2 * 8 + i] = f2bf(W[k * 64 + col]);
    }
}

// ---------------------------------------------------------------------------
// CSR build pass 1: histogram + per-edge rank (the atomicAdd return value).
// ---------------------------------------------------------------------------
__global__ void hist_kernel(const int* __restrict__ ei, int* __restrict__ count,
                            int* __restrict__ rank, int E, int n) {
    int j = blockIdx.x * blockDim.x + threadIdx.x;
    if (j < E) {
        int d = clampi(ei[E + j], 0, n - 1);
        rank[j] = atomicAdd(&count[d], 1);
    }
}

// Exclusive scan, single block of 1024 threads, 4 elements per thread per pass.
__global__ void scan_exclusive(const int* __restrict__ count, int* __restrict__ row_ptr,
                               int n) {
    __shared__ int wsum[16];
    int tid = threadIdx.x, lane = tid & 63, wv = tid >> 6;
    int carry = 0;
    for (int base = 0; base < n; base += 4096) {
        int i4 = base + tid * 4;
        int v0 = 0, v1 = 0, v2 = 0, v3 = 0;
        if (i4 + 3 < n) {
            int4 t = *(const int4*)(count + i4);
            v0 = t.x; v1 = t.y; v2 = t.z; v3 = t.w;
        } else {
            if (i4     < n) v0 = count[i4];
            if (i4 + 1 < n) v1 = count[i4 + 1];
            if (i4 + 2 < n) v2 = count[i4 + 2];
            if (i4 + 3 < n) v3 = count[i4 + 3];
        }
        int s0 = v0, s1 = s0 + v1, s2 = s1 + v2, s3 = s2 + v3;
        int sv = s3;
        #pragma unroll
        for (int off = 1; off < 64; off <<= 1) {
            int t = __shfl_up(sv, off, 64);
            if (lane >= off) sv += t;
        }
        if (lane == 63) wsum[wv] = sv;
        __syncthreads();
        if (tid < 16) {
            int ws = wsum[tid];
            #pragma unroll
            for (int off = 1; off < 16; off <<= 1) {
                int t = __shfl_up(ws, off, 64);
                if (tid >= off) ws += t;
            }
            wsum[tid] = ws;
        }
        __syncthreads();
        int add = carry + (wv ? wsum[wv - 1] : 0) + (sv - s3);
        if (i4     < n) row_ptr[i4]     = add;
        if (i4 + 1 < n) row_ptr[i4 + 1] = add + s0;
        if (i4 + 2 < n) row_ptr[i4 + 2] = add + s1;
        if (i4 + 3 < n) row_ptr[i4 + 3] = add + s2;
        carry += wsum[15];
        __syncthreads();
    }
    if (tid == 0) row_ptr[n] = carry;
}

// CSR build pass 2: ATOMIC-FREE scatter. pos = row_ptr[dst] + rank[edge].
__global__ void scatter_kernel(const int* __restrict__ ei, const float* __restrict__ ea,
                               const int* __restrict__ rank, const int* __restrict__ row_ptr,
                               uint* __restrict__ cse, int E, int n) {
    int j = blockIdx.x * blockDim.x + threadIdx.x;
    if (j < E) {
        int d = clampi(ei[E + j], 0, n - 1);
        int pos = row_ptr[d] + rank[j];
        if (pos >= 0 && pos < E)
            cse[pos] = pack_edge(clampi(ei[j], 0, n - 1), ea[j]);
    }
}

// ---------------------------------------------------------------------------
// Degree-balanced node ordering (counting sort by min(degree,63)).
// agg3 waves then process equal-degree nodes -> no max-of-8 trip divergence.
// ---------------------------------------------------------------------------
__global__ void deg_hist(const int* __restrict__ row_ptr, int* __restrict__ dcount,
                         int* __restrict__ nrank, int n) {
    int i = blockIdx.x * blockDim.x + threadIdx.x;
    if (i < n) {
        int deg = clampi(row_ptr[i + 1] - row_ptr[i], 0, 63);
        nrank[i] = atomicAdd(&dcount[deg], 1);
    }
}

__global__ void dscan_kernel(const int* __restrict__ dcount, int* __restrict__ dbase) {
    int lane = threadIdx.x;            // blockDim.x == 64
    int v = dcount[lane];
    int sv = v;
    #pragma unroll
    for (int off = 1; off < 64; off <<= 1) {
        int t = __shfl_up(sv, off, 64);
        if (lane >= off) sv += t;
    }
    dbase[lane] = sv - v;
}

__global__ void dscatter_kernel(const int* __restrict__ row_ptr, const int* __restrict__ dbase,
                                const int* __restrict__ nrank, int* __restrict__ order, int n) {
    int i = blockIdx.x * blockDim.x + threadIdx.x;
    if (i < n) {
        int deg = clampi(row_ptr[i + 1] - row_ptr[i], 0, 63);
        int pos = dbase[deg] + nrank[i];
        if (pos >= 0 && pos < n) order[pos] = i;
    }
}

// ---------------------------------------------------------------------------
// Node transform via MFMA, biases folded. One wave = 16-row x 256-col tile
// (Q|K|V|S) in 32 MFMAs. Epilogue stages the tile in per-wave LDS, then
// emits 10 coalesced global_store_dwordx4 per tile (vs 64 scalar stores).
// Outputs: Qb bf16, KV interleaved bf16 [row][128], S f32, qWe = (Q+bq).We.
// ---------------------------------------------------------------------------
#define QT_STRIDE 72    // ushorts per row (pad: 144B, bank rotation 4)
#define KV_STRIDE 136   // ushorts per row (272B)
#define ST_STRIDE 68    // floats per row (272B)

template<bool INF32>
__global__ __launch_bounds__(256) void node_transform_mfma(
    const void* __restrict__ xin, const ushort* __restrict__ Bpack,
    const float* __restrict__ We,
    const float* __restrict__ bq, const float* __restrict__ bk,
    const float* __restrict__ bv, const float* __restrict__ bs,
    ushort* __restrict__ Qb, ushort* __restrict__ KVb,
    float* __restrict__ S, float* __restrict__ qWe, int n)
{
    __shared__ bshort8 Blds[2048];                 // 32 KiB
    __shared__ ushort qlds[4 * 16 * QT_STRIDE];    // 9216 B
    __shared__ ushort kvlds[4 * 16 * KV_STRIDE];   // 17408 B
    __shared__ float  slds[4 * 16 * ST_STRIDE];    // 17408 B
    {
        const bshort8* gB = (const bshort8*)Bpack;
        for (int i = threadIdx.x; i < 2048; i += 256) Blds[i] = gB[i];
    }
    __syncthreads();

    int lane = threadIdx.x & 63;
    int wv = threadIdx.x >> 6;
    int tile = blockIdx.x * 4 + wv;
    int ntiles = (n + 15) >> 4;
    if (tile >= ntiles) return;
    int r0 = tile << 4;
    int c = lane & 15, g = lane >> 4;

    int arow = r0 + c; if (arow >= n) arow = n - 1;
    union { ushort4 u[2]; bshort8 v; } A0, A1;
    if constexpr (INF32) {
        const float* xr = (const float*)xin + (size_t)arow * 64 + 4 * g;
        float4 f0 = *(const float4*)(xr);
        float4 f1 = *(const float4*)(xr + 16);
        float4 f2 = *(const float4*)(xr + 32);
        float4 f3 = *(const float4*)(xr + 48);
        A0.u[0] = make_ushort4(f2bf(f0.x), f2bf(f0.y), f2bf(f0.z), f2bf(f0.w));
        A0.u[1] = make_ushort4(f2bf(f1.x), f2bf(f1.y), f2bf(f1.z), f2bf(f1.w));
        A1.u[0] = make_ushort4(f2bf(f2.x), f2bf(f2.y), f2bf(f2.z), f2bf(f2.w));
        A1.u[1] = make_ushort4(f2bf(f3.x), f2bf(f3.y), f2bf(f3.z), f2bf(f3.w));
    } else {
        const ushort* xr = (const ushort*)xin + (size_t)arow * 64 + 4 * g;
        A0.u[0] = *(const ushort4*)(xr);
        A0.u[1] = *(const ushort4*)(xr + 16);
        A1.u[0] = *(const ushort4*)(xr + 32);
        A1.u[1] = *(const ushort4*)(xr + 48);
    }

    f32x4 acc[16];
    #pragma unroll
    for (int t = 0; t < 16; ++t) acc[t] = (f32x4){0.f, 0.f, 0.f, 0.f};
    #pragma unroll
    for (int t = 0; t < 16; ++t) {
        acc[t] = __builtin_amdgcn_mfma_f32_16x16x32_bf16(A0.v, Blds[(2 * t) * 64 + lane], acc[t], 0, 0, 0);
        acc[t] = __builtin_amdgcn_mfma_f32_16x16x32_bf16(A1.v, Blds[(2 * t + 1) * 64 + lane], acc[t], 0, 0, 0);
    }

    float we_c[4], bq_c[4];
    #pragma unroll
    for (int t = 0; t < 4; ++t) { we_c[t] = We[16 * t + c]; bq_c[t] = bq[16 * t + c]; }
    #pragma unroll
    for (int j = 0; j < 4; ++j) {
        float part = 0.f;
        #pragma unroll
        for (int t = 0; t < 4; ++t) part += (acc[t][j] + bq_c[t]) * we_c[t];
        part += __shfl_xor(part, 1);
        part += __shfl_xor(part, 2);
        part += __shfl_xor(part, 4);
        part += __shfl_xor(part, 8);
        int orow = r0 + 4 * g + j;
        if (c == 0 && orow < n) qWe[orow] = part;
    }

    // ---- stage the tile in this wave's LDS slice (fragment layout -> row-major)
    ushort* qt = qlds + wv * 16 * QT_STRIDE;
    ushort* kt = kvlds + wv * 16 * KV_STRIDE;
    float*  st = slds + wv * 16 * ST_STRIDE;
    #pragma unroll
    for (int tt = 0; tt < 4; ++tt) {
        int col = 16 * tt + c;
        float vbk = bk[col], vbv = bv[col], vbs = bs[col];
        #pragma unroll
        for (int j = 0; j < 4; ++j) {
            int row = 4 * g + j;
            qt[row * QT_STRIDE + col]      = f2bf(acc[tt][j] + bq_c[tt]);
            kt[row * KV_STRIDE + col]      = f2bf(acc[4 + tt][j] + vbk);
            kt[row * KV_STRIDE + 64 + col] = f2bf(acc[8 + tt][j] + vbv);
            st[row * ST_STRIDE + col]      = acc[12 + tt][j] + vbs;
        }
    }

    // ---- coalesced readout: 2 + 4 + 4 wide stores per lane
    #pragma unroll
    for (int k2 = 0; k2 < 2; ++k2) {            // Qb: 128 chunks of 8 ushorts
        int ch = k2 * 64 + lane;
        int row = ch >> 3, off = ch & 7;
        if (r0 + row < n)
            *(ushort8v*)(Qb + (size_t)(r0 + row) * 64 + off * 8) =
                *(const ushort8v*)(qt + row * QT_STRIDE + off * 8);
    }
    #pragma unroll
    for (int k4 = 0; k4 < 4; ++k4) {            // KVb: 256 chunks of 8 ushorts
        int ch = k4 * 64 + lane;
        int row = ch >> 4, off = ch & 15;
        if (r0 + row < n)
            *(ushort8v*)(KVb + (size_t)(r0 + row) * 128 + off * 8) =
                *(const ushort8v*)(kt + row * KV_STRIDE + off * 8);
    }
    #pragma unroll
    for (int k4 = 0; k4 < 4; ++k4) {            // S: 256 chunks of float4
        int ch = k4 * 64 + lane;
        int row = ch >> 4, off = ch & 15;
        if (r0 + row < n)
            *(float4*)(S + (size_t)(r0 + row) * 64 + off * 4) =
                *(const float4*)(st + row * ST_STRIDE + off * 4);
    }
}

// ---------------------------------------------------------------------------
// Fused attention aggregate: one 8-lane group per dst node, nodes visited in
// degree-sorted order (order[]) so a wave's 8 groups have equal trip counts.
// Per edge: 4B record broadcast, K+V halves of one 256B row, 8-wide dot + 3
// shuffles, exp per lane, shuffle-free accumulate. Unrolled x2.
// out = (sum p*V)/sum p + (sum p*ea)/sum p * We + S   (+relu, bf16 for L1).
// ---------------------------------------------------------------------------
template<int L1>
__global__ __launch_bounds__(256) void agg3_kernel(
    const ushort* __restrict__ Qb, const ushort* __restrict__ KVb,
    const float* __restrict__ S, const float* __restrict__ qWe,
    const float* __restrict__ We, const int* __restrict__ row_ptr,
    const uint* __restrict__ cse, const int* __restrict__ order,
    void* __restrict__ outp, int n, int E)
{
    int q8 = threadIdx.x & 7;
    int gid = (blockIdx.x * blockDim.x + threadIdx.x) >> 3;
    int ng  = (gridDim.x * blockDim.x) >> 3;
    float4 weA = ((const float4*)We)[2 * q8];
    float4 weB = ((const float4*)We)[2 * q8 + 1];

    for (int ii = gid; ii < n; ii += ng) {
        int i = clampi(order[ii], 0, n - 1);
        int beg = clampi(row_ptr[i], 0, E);
        int end = clampi(row_ptr[i + 1], beg, E);
        ushort8v q8v = *(const ushort8v*)(Qb + (size_t)i * 64 + 8 * q8);
        float4 qA = make_float4(bf2f(q8v[0]), bf2f(q8v[1]), bf2f(q8v[2]), bf2f(q8v[3]));
        float4 qB = make_float4(bf2f(q8v[4]), bf2f(q8v[5]), bf2f(q8v[6]), bf2f(q8v[7]));
        float qwe8 = qWe[i] * 0.125f;
        f32x4 aA = {0.f, 0.f, 0.f, 0.f}, aB = {0.f, 0.f, 0.f, 0.f};
        float ssum = 0.f, sea = 0.f;

        int e = beg;
        for (; e + 2 <= end; e += 2) {
            uint ed0 = cse[e], ed1 = cse[e + 1];
            const ushort* r0 = KVb + (size_t)clampi(rec_src(ed0), 0, n - 1) * 128 + 8 * q8;
            const ushort* r1 = KVb + (size_t)clampi(rec_src(ed1), 0, n - 1) * 128 + 8 * q8;
            ushort8v k0 = *(const ushort8v*)(r0);
            ushort8v v0 = *(const ushort8v*)(r0 + 64);
            ushort8v k1 = *(const ushort8v*)(r1);
            ushort8v v1 = *(const ushort8v*)(r1 + 64);
            float ea0 = rec_ea(ed0), ea1 = rec_ea(ed1);
            float d0 = dot8(qA, qB, k0);
            float d1 = dot8(qA, qB, k1);
            d0 += __shfl_xor(d0, 1); d1 += __shfl_xor(d1, 1);
            d0 += __shfl_xor(d0, 2); d1 += __shfl_xor(d1, 2);
            d0 += __shfl_xor(d0, 4); d1 += __shfl_xor(d1, 4);
            float p0 = __expf(fmaf(ea0, qwe8, d0 * 0.125f));
            float p1 = __expf(fmaf(ea1, qwe8, d1 * 0.125f));
            ssum += p0 + p1;
            sea = fmaf(p0, ea0, fmaf(p1, ea1, sea));
            aA[0] = fmaf(p0, bf2f(v0[0]), fmaf(p1, bf2f(v1[0]), aA[0]));
            aA[1] = fmaf(p0, bf2f(v0[1]), fmaf(p1, bf2f(v1[1]), aA[1]));
            aA[2] = fmaf(p0, bf2f(v0[2]), fmaf(p1, bf2f(v1[2]), aA[2]));
            aA[3] = fmaf(p0, bf2f(v0[3]), fmaf(p1, bf2f(v1[3]), aA[3]));
            aB[0] = fmaf(p0, bf2f(v0[4]), fmaf(p1, bf2f(v1[4]), aB[0]));
            aB[1] = fmaf(p0, bf2f(v0[5]), fmaf(p1, bf2f(v1[5]), aB[1]));
            aB[2] = fmaf(p0, bf2f(v0[6]), fmaf(p1, bf2f(v1[6]), aB[2]));
            aB[3] = fmaf(p0, bf2f(v0[7]), fmaf(p1, bf2f(v1[7]), aB[3]));
        }
        if (e < end) {
            uint ed = cse[e];
            const ushort* row = KVb + (size_t)clampi(rec_src(ed), 0, n - 1) * 128 + 8 * q8;
            ushort8v k0 = *(const ushort8v*)(row);
            ushort8v v0 = *(const ushort8v*)(row + 64);
            float ea0 = rec_ea(ed);
            float d0 = dot8(qA, qB, k0);
            d0 += __shfl_xor(d0, 1);
            d0 += __shfl_xor(d0, 2);
            d0 += __shfl_xor(d0, 4);
            float p0 = __expf(fmaf(ea0, qwe8, d0 * 0.125f));
            ssum += p0;
            sea = fmaf(p0, ea0, sea);
            aA[0] = fmaf(p0, bf2f(v0[0]), aA[0]);
            aA[1] = fmaf(p0, bf2f(v0[1]), aA[1]);
            aA[2] = fmaf(p0, bf2f(v0[2]), aA[2]);
            aA[3] = fmaf(p0, bf2f(v0[3]), aA[3]);
            aB[0] = fmaf(p0, bf2f(v0[4]), aB[0]);
            aB[1] = fmaf(p0, bf2f(v0[5]), aB[1]);
            aB[2] = fmaf(p0, bf2f(v0[6]), aB[2]);
            aB[3] = fmaf(p0, bf2f(v0[7]), aB[3]);
        }

        float inv = (ssum > 0.f) ? 1.f / ssum : 0.f;
        float eawe = sea * inv;
        const float4* Srow = (const float4*)(S + (size_t)i * 64);
        float4 sA = Srow[2 * q8], sB = Srow[2 * q8 + 1];
        float o0 = fmaf(aA[0], inv, fmaf(eawe, weA.x, sA.x));
        float o1 = fmaf(aA[1], inv, fmaf(eawe, weA.y, sA.y));
        float o2 = fmaf(aA[2], inv, fmaf(eawe, weA.z, sA.z));
        float o3 = fmaf(aA[3], inv, fmaf(eawe, weA.w, sA.w));
        float o4 = fmaf(aB[0], inv, fmaf(eawe, weB.x, sB.x));
        float o5 = fmaf(aB[1], inv, fmaf(eawe, weB.y, sB.y));
        float o6 = fmaf(aB[2], inv, fmaf(eawe, weB.z, sB.z));
        float o7 = fmaf(aB[3], inv, fmaf(eawe, weB.w, sB.w));
        if (L1) {
            o0 = fmaxf(o0, 0.f); o1 = fmaxf(o1, 0.f); o2 = fmaxf(o2, 0.f); o3 = fmaxf(o3, 0.f);
            o4 = fmaxf(o4, 0.f); o5 = fmaxf(o5, 0.f); o6 = fmaxf(o6, 0.f); o7 = fmaxf(o7, 0.f);
            union { ushort u[8]; ushort8v v; } ov;
            ov.u[0] = f2bf(o0); ov.u[1] = f2bf(o1); ov.u[2] = f2bf(o2); ov.u[3] = f2bf(o3);
            ov.u[4] = f2bf(o4); ov.u[5] = f2bf(o5); ov.u[6] = f2bf(o6); ov.u[7] = f2bf(o7);
            *(ushort8v*)((ushort*)outp + (size_t)i * 64 + 8 * q8) = ov.v;
        } else {
            float4* Or = (float4*)((float*)outp + (size_t)i * 64);
            Or[2 * q8]     = make_float4(o0, o1, o2, o3);
            Or[2 * q8 + 1] = make_float4(o4, o5, o6, o7);
        }
    }
}

// ---------------------------------------------------------------------------
extern "C" void kernel_launch(void* const* d_in, const int* in_sizes, int n_in,
                              void* d_out, int out_size, void* d_ws, size_t ws_size,
                              hipStream_t stream) {
    const float* x   = (const float*)d_in[0];
    const int*   ei  = (const int*)d_in[1];     // int32 on device
    const float* ea  = (const float*)d_in[2];
    const float *Wq1 = (const float*)d_in[3],  *bq1 = (const float*)d_in[4];
    const float *Wk1 = (const float*)d_in[5],  *bk1 = (const float*)d_in[6];
    const float *Wv1 = (const float*)d_in[7],  *bv1 = (const float*)d_in[8];
    const float *We1 = (const float*)d_in[9];
    const float *Ws1 = (const float*)d_in[10], *bs1 = (const float*)d_in[11];
    const float *Wq2 = (const float*)d_in[12], *bq2 = (const float*)d_in[13];
    const float *Wk2 = (const float*)d_in[14], *bk2 = (const float*)d_in[15];
    const float *Wv2 = (const float*)d_in[16], *bv2 = (const float*)d_in[17];
    const float *We2 = (const float*)d_in[18];
    const float *Ws2 = (const float*)d_in[19], *bs2 = (const float*)d_in[20];

    const int N_ = in_sizes[0] / 64;   // 50000
    const int E_ = in_sizes[2];        // 800000

    char* wsb = (char*)d_ws;
    size_t off = 0;
    auto carve = [&](size_t bytes) -> void* {
        void* p = (void*)(wsb + off);
        off += (bytes + 255) & ~(size_t)255;
        return p;
    };
    ushort* Qb   = (ushort*)carve((size_t)N_ * 64 * 2);
    float*  S    = (float*)carve((size_t)N_ * 64 * 4);
    ushort* KVb  = (ushort*)carve((size_t)N_ * 128 * 2);
    ushort* hb   = (ushort*)carve((size_t)N_ * 64 * 2);
    float*  qWe  = (float*)carve((size_t)N_ * 4);
    int*    count   = (int*)carve((size_t)N_ * 4);
    int*    row_ptr = (int*)carve((size_t)(N_ + 1) * 4);
    int*    rank    = (int*)carve((size_t)E_ * 4);
    uint*   cse     = (uint*)carve((size_t)E_ * 4);
    int*    nrank   = (int*)carve((size_t)N_ * 4);
    int*    order   = (int*)carve((size_t)N_ * 4);
    int*    dcount  = (int*)carve(64 * 4);
    int*    dbase   = (int*)carve(64 * 4);
    ushort* Bp1     = (ushort*)carve(2048 * 8 * 2);
    ushort* Bp2     = (ushort*)carve(2048 * 8 * 2);
    (void)ws_size; (void)n_in; (void)out_size;

    pack_and_zero<<<16 + (N_ + 255) / 256, 256, 0, stream>>>(
        Wq1, Wk1, Wv1, Ws1, Wq2, Wk2, Wv2, Ws2, Bp1, Bp2, count, dcount, N_);

    // CSR build (atomic-free scatter via hist ranks)
    hist_kernel<<<(E_ + 255) / 256, 256, 0, stream>>>(ei, count, rank, E_, N_);
    scan_exclusive<<<1, 1024, 0, stream>>>(count, row_ptr, N_);
    scatter_kernel<<<(E_ + 255) / 256, 256, 0, stream>>>(ei, ea, rank, row_ptr, cse, E_, N_);

    // Degree-sorted node order (counting sort, reuses the rank trick)
    deg_hist<<<(N_ + 255) / 256, 256, 0, stream>>>(row_ptr, dcount, nrank, N_);
    dscan_kernel<<<1, 64, 0, stream>>>(dcount, dbase);
    dscatter_kernel<<<(N_ + 255) / 256, 256, 0, stream>>>(row_ptr, dbase, nrank, order, N_);

    int ntb = (((N_ + 15) / 16) + 3) / 4;

    // Layer 1
    node_transform_mfma<true><<<ntb, 256, 0, stream>>>(x, Bp1, We1, bq1, bk1, bv1, bs1,
                                                       Qb, KVb, S, qWe, N_);
    agg3_kernel<1><<<1568, 256, 0, stream>>>(Qb, KVb, S, qWe, We1, row_ptr, cse, order,
                                             hb, N_, E_);
    // Layer 2
    node_transform_mfma<false><<<ntb, 256, 0, stream>>>(hb, Bp2, We2, bq2, bk2, bv2, bs2,
                                                        Qb, KVb, S, qWe, N_);
    agg3_kernel<0><<<1568, 256, 0, stream>>>(Qb, KVb, S, qWe, We2, row_ptr, cse, order,
                                             d_out, N_, E_);
}

// Round 15
// 193.476 us; speedup vs baseline: 1.6755x; 1.6755x over previous
//
#include <hip/hip_runtime.h>
#include <hip/hip_bf16.h>
#include <hip/hip_fp16.h>

typedef short bshort8 __attribute__((ext_vector_type(8)));
typedef float f32x4 __attribute__((ext_vector_type(4)));
typedef unsigned short ushort8v __attribute__((ext_vector_type(8)));

__device__ __forceinline__ int clampi(int v, int lo, int hi) {
    return v < lo ? lo : (v > hi ? hi : v);
}
__device__ __forceinline__ ushort f2bf(float f) {           // RNE f32 -> bf16 bits
    uint u = __float_as_uint(f);
    return (ushort)((u + 0x7FFFu + ((u >> 16) & 1u)) >> 16);
}
__device__ __forceinline__ float bf2f(ushort b) { return __uint_as_float(((uint)b) << 16); }

__device__ __forceinline__ float dot8(float4 qA, float4 qB, ushort8v k8) {
    return qA.x * bf2f(k8[0]) + qA.y * bf2f(k8[1]) + qA.z * bf2f(k8[2]) + qA.w * bf2f(k8[3])
         + qB.x * bf2f(k8[4]) + qB.y * bf2f(k8[5]) + qB.z * bf2f(k8[6]) + qB.w * bf2f(k8[7]);
}

// Edge record: src in bits [31:15] (17b), ea as fp16>>1 in bits [14:0].
__device__ __forceinline__ uint pack_edge(int src, float ea) {
    ushort h = __half_as_ushort(__float2half(ea));
    return ((uint)src << 15) | ((uint)(h >> 1) & 0x7FFFu);
}
__device__ __forceinline__ int rec_src(uint r) { return (int)(r >> 15); }
__device__ __forceinline__ float rec_ea(uint r) {
    return __half2float(__ushort_as_half((ushort)((r & 0x7FFFu) << 1)));
}

// ---------------------------------------------------------------------------
// Pack both layers' weights into per-lane MFMA B-fragments (blocks 0..15);
// zero histogram counters + degree bins (blocks >= 16).
// ---------------------------------------------------------------------------
__global__ void pack_and_zero(const float* __restrict__ Wq1, const float* __restrict__ Wk1,
                              const float* __restrict__ Wv1, const float* __restrict__ Ws1,
                              const float* __restrict__ Wq2, const float* __restrict__ Wk2,
                              const float* __restrict__ Wv2, const float* __restrict__ Ws2,
                              ushort* __restrict__ Bp1, ushort* __restrict__ Bp2,
                              int* __restrict__ count, int* __restrict__ dcount, int n) {
    if (blockIdx.x >= 16) {
        int j = (blockIdx.x - 16) * 256 + threadIdx.x;
        if (j < n) count[j] = 0;
        if (blockIdx.x == 16 && threadIdx.x < 64) dcount[threadIdx.x] = 0;
        return;
    }
    int tid = blockIdx.x * 256 + threadIdx.x;          // 0..4095
    int layer = tid >> 11;
    int t2 = tid & 2047;
    int lane = t2 & 63;
    int th = t2 >> 6;                  // t*2 + h
    int h = th & 1, t = th >> 1;
    const float* W = layer ? ((t < 4) ? Wq2 : (t < 8) ? Wk2 : (t < 12) ? Wv2 : Ws2)
                           : ((t < 4) ? Wq1 : (t < 8) ? Wk1 : (t < 12) ? Wv1 : Ws1);
    ushort* Bp = layer ? Bp2 : Bp1;
    int col = ((t & 3) << 4) + (lane & 15);
    int g = lane >> 4;
    #pragma unroll
    for (int i = 0; i < 8; ++i) {
        int k = 32 * h + 16 * (i >> 2) + 4 * g + (i & 3);
        Bp[t2 * 8 + i] = f2bf(W[k * 64 + col]);
    }
}

// ---------------------------------------------------------------------------
// CSR build pass 1: histogram + per-edge rank (the atomicAdd return value).
// ---------------------------------------------------------------------------
__global__ void hist_kernel(const int* __restrict__ ei, int* __restrict__ count,
                            int* __restrict__ rank, int E, int n) {
    int j = blockIdx.x * blockDim.x + threadIdx.x;
    if (j < E) {
        int d = clampi(ei[E + j], 0, n - 1);
        rank[j] = atomicAdd(&count[d], 1);
    }
}

// Exclusive scan, single block of 1024 threads, 4 elements per thread per pass.
__global__ void scan_exclusive(const int* __restrict__ count, int* __restrict__ row_ptr,
                               int n) {
    __shared__ int wsum[16];
    int tid = threadIdx.x, lane = tid & 63, wv = tid >> 6;
    int carry = 0;
    for (int base = 0; base < n; base += 4096) {
        int i4 = base + tid * 4;
        int v0 = 0, v1 = 0, v2 = 0, v3 = 0;
        if (i4 + 3 < n) {
            int4 t = *(const int4*)(count + i4);
            v0 = t.x; v1 = t.y; v2 = t.z; v3 = t.w;
        } else {
            if (i4     < n) v0 = count[i4];
            if (i4 + 1 < n) v1 = count[i4 + 1];
            if (i4 + 2 < n) v2 = count[i4 + 2];
            if (i4 + 3 < n) v3 = count[i4 + 3];
        }
        int s0 = v0, s1 = s0 + v1, s2 = s1 + v2, s3 = s2 + v3;
        int sv = s3;
        #pragma unroll
        for (int off = 1; off < 64; off <<= 1) {
            int t = __shfl_up(sv, off, 64);
            if (lane >= off) sv += t;
        }
        if (lane == 63) wsum[wv] = sv;
        __syncthreads();
        if (tid < 16) {
            int ws = wsum[tid];
            #pragma unroll
            for (int off = 1; off < 16; off <<= 1) {
                int t = __shfl_up(ws, off, 64);
                if (tid >= off) ws += t;
            }
            wsum[tid] = ws;
        }
        __syncthreads();
        int add = carry + (wv ? wsum[wv - 1] : 0) + (sv - s3);
        if (i4     < n) row_ptr[i4]     = add;
        if (i4 + 1 < n) row_ptr[i4 + 1] = add + s0;
        if (i4 + 2 < n) row_ptr[i4 + 2] = add + s1;
        if (i4 + 3 < n) row_ptr[i4 + 3] = add + s2;
        carry += wsum[15];
        __syncthreads();
    }
    if (tid == 0) row_ptr[n] = carry;
}

// CSR build pass 2: ATOMIC-FREE scatter. pos = row_ptr[dst] + rank[edge].
__global__ void scatter_kernel(const int* __restrict__ ei, const float* __restrict__ ea,
                               const int* __restrict__ rank, const int* __restrict__ row_ptr,
                               uint* __restrict__ cse, int E, int n) {
    int j = blockIdx.x * blockDim.x + threadIdx.x;
    if (j < E) {
        int d = clampi(ei[E + j], 0, n - 1);
        int pos = row_ptr[d] + rank[j];
        if (pos >= 0 && pos < E)
            cse[pos] = pack_edge(clampi(ei[j], 0, n - 1), ea[j]);
    }
}

// ---------------------------------------------------------------------------
// Degree-balanced node ordering (counting sort by min(degree,63)).
// deg_hist: LDS-staged two-level histogram -- 64-bin LDS atomics per block,
// then ONE global atomic per non-empty bin per block (r14 lesson: 50k global
// atomics on 64 addresses serialized = 133us).
// ---------------------------------------------------------------------------
__global__ void deg_hist(const int* __restrict__ row_ptr, int* __restrict__ dcount,
                         int* __restrict__ nrank, int n) {
    __shared__ int lbin[64];
    __shared__ int lbase[64];
    int tid = threadIdx.x;
    if (tid < 64) lbin[tid] = 0;
    __syncthreads();
    int i = blockIdx.x * blockDim.x + tid;
    int deg = 0, lr = 0;
    if (i < n) {
        deg = clampi(row_ptr[i + 1] - row_ptr[i], 0, 63);
        lr = atomicAdd(&lbin[deg], 1);
    }
    __syncthreads();
    if (tid < 64) lbase[tid] = lbin[tid] ? atomicAdd(&dcount[tid], lbin[tid]) : 0;
    __syncthreads();
    if (i < n) nrank[i] = lbase[deg] + lr;
}

__global__ void dscan_kernel(const int* __restrict__ dcount, int* __restrict__ dbase) {
    int lane = threadIdx.x;            // blockDim.x == 64
    int v = dcount[lane];
    int sv = v;
    #pragma unroll
    for (int off = 1; off < 64; off <<= 1) {
        int t = __shfl_up(sv, off, 64);
        if (lane >= off) sv += t;
    }
    dbase[lane] = sv - v;
}

__global__ void dscatter_kernel(const int* __restrict__ row_ptr, const int* __restrict__ dbase,
                                const int* __restrict__ nrank, int* __restrict__ order, int n) {
    int i = blockIdx.x * blockDim.x + threadIdx.x;
    if (i < n) {
        int deg = clampi(row_ptr[i + 1] - row_ptr[i], 0, 63);
        int pos = dbase[deg] + nrank[i];
        if (pos >= 0 && pos < n) order[pos] = i;
    }
}

// ---------------------------------------------------------------------------
// Node transform via MFMA, biases folded. One wave = 16-row x 256-col tile
// (Q|K|V|S) in 32 MFMAs. Epilogue stages the tile in per-wave LDS, then
// emits 10 coalesced global_store_dwordx4 per tile (vs 64 scalar stores).
// Outputs: Qb bf16, KV interleaved bf16 [row][128], S f32, qWe = (Q+bq).We.
// ---------------------------------------------------------------------------
#define QT_STRIDE 72    // ushorts per row (pad: 144B, bank rotation 4)
#define KV_STRIDE 136   // ushorts per row (272B)
#define ST_STRIDE 68    // floats per row (272B)

template<bool INF32>
__global__ __launch_bounds__(256) void node_transform_mfma(
    const void* __restrict__ xin, const ushort* __restrict__ Bpack,
    const float* __restrict__ We,
    const float* __restrict__ bq, const float* __restrict__ bk,
    const float* __restrict__ bv, const float* __restrict__ bs,
    ushort* __restrict__ Qb, ushort* __restrict__ KVb,
    float* __restrict__ S, float* __restrict__ qWe, int n)
{
    __shared__ bshort8 Blds[2048];                 // 32 KiB
    __shared__ ushort qlds[4 * 16 * QT_STRIDE];    // 9216 B
    __shared__ ushort kvlds[4 * 16 * KV_STRIDE];   // 17408 B
    __shared__ float  slds[4 * 16 * ST_STRIDE];    // 17408 B
    {
        const bshort8* gB = (const bshort8*)Bpack;
        for (int i = threadIdx.x; i < 2048; i += 256) Blds[i] = gB[i];
    }
    __syncthreads();

    int lane = threadIdx.x & 63;
    int wv = threadIdx.x >> 6;
    int tile = blockIdx.x * 4 + wv;
    int ntiles = (n + 15) >> 4;
    if (tile >= ntiles) return;
    int r0 = tile << 4;
    int c = lane & 15, g = lane >> 4;

    int arow = r0 + c; if (arow >= n) arow = n - 1;
    union { ushort4 u[2]; bshort8 v; } A0, A1;
    if constexpr (INF32) {
        const float* xr = (const float*)xin + (size_t)arow * 64 + 4 * g;
        float4 f0 = *(const float4*)(xr);
        float4 f1 = *(const float4*)(xr + 16);
        float4 f2 = *(const float4*)(xr + 32);
        float4 f3 = *(const float4*)(xr + 48);
        A0.u[0] = make_ushort4(f2bf(f0.x), f2bf(f0.y), f2bf(f0.z), f2bf(f0.w));
        A0.u[1] = make_ushort4(f2bf(f1.x), f2bf(f1.y), f2bf(f1.z), f2bf(f1.w));
        A1.u[0] = make_ushort4(f2bf(f2.x), f2bf(f2.y), f2bf(f2.z), f2bf(f2.w));
        A1.u[1] = make_ushort4(f2bf(f3.x), f2bf(f3.y), f2bf(f3.z), f2bf(f3.w));
    } else {
        const ushort* xr = (const ushort*)xin + (size_t)arow * 64 + 4 * g;
        A0.u[0] = *(const ushort4*)(xr);
        A0.u[1] = *(const ushort4*)(xr + 16);
        A1.u[0] = *(const ushort4*)(xr + 32);
        A1.u[1] = *(const ushort4*)(xr + 48);
    }

    f32x4 acc[16];
    #pragma unroll
    for (int t = 0; t < 16; ++t) acc[t] = (f32x4){0.f, 0.f, 0.f, 0.f};
    #pragma unroll
    for (int t = 0; t < 16; ++t) {
        acc[t] = __builtin_amdgcn_mfma_f32_16x16x32_bf16(A0.v, Blds[(2 * t) * 64 + lane], acc[t], 0, 0, 0);
        acc[t] = __builtin_amdgcn_mfma_f32_16x16x32_bf16(A1.v, Blds[(2 * t + 1) * 64 + lane], acc[t], 0, 0, 0);
    }

    float we_c[4], bq_c[4];
    #pragma unroll
    for (int t = 0; t < 4; ++t) { we_c[t] = We[16 * t + c]; bq_c[t] = bq[16 * t + c]; }
    #pragma unroll
    for (int j = 0; j < 4; ++j) {
        float part = 0.f;
        #pragma unroll
        for (int t = 0; t < 4; ++t) part += (acc[t][j] + bq_c[t]) * we_c[t];
        part += __shfl_xor(part, 1);
        part += __shfl_xor(part, 2);
        part += __shfl_xor(part, 4);
        part += __shfl_xor(part, 8);
        int orow = r0 + 4 * g + j;
        if (c == 0 && orow < n) qWe[orow] = part;
    }

    // ---- stage the tile in this wave's LDS slice (fragment layout -> row-major)
    ushort* qt = qlds + wv * 16 * QT_STRIDE;
    ushort* kt = kvlds + wv * 16 * KV_STRIDE;
    float*  st = slds + wv * 16 * ST_STRIDE;
    #pragma unroll
    for (int tt = 0; tt < 4; ++tt) {
        int col = 16 * tt + c;
        float vbk = bk[col], vbv = bv[col], vbs = bs[col];
        #pragma unroll
        for (int j = 0; j < 4; ++j) {
            int row = 4 * g + j;
            qt[row * QT_STRIDE + col]      = f2bf(acc[tt][j] + bq_c[tt]);
            kt[row * KV_STRIDE + col]      = f2bf(acc[4 + tt][j] + vbk);
            kt[row * KV_STRIDE + 64 + col] = f2bf(acc[8 + tt][j] + vbv);
            st[row * ST_STRIDE + col]      = acc[12 + tt][j] + vbs;
        }
    }

    // ---- coalesced readout: 2 + 4 + 4 wide stores per lane
    #pragma unroll
    for (int k2 = 0; k2 < 2; ++k2) {            // Qb: 128 chunks of 8 ushorts
        int ch = k2 * 64 + lane;
        int row = ch >> 3, off = ch & 7;
        if (r0 + row < n)
            *(ushort8v*)(Qb + (size_t)(r0 + row) * 64 + off * 8) =
                *(const ushort8v*)(qt + row * QT_STRIDE + off * 8);
    }
    #pragma unroll
    for (int k4 = 0; k4 < 4; ++k4) {            // KVb: 256 chunks of 8 ushorts
        int ch = k4 * 64 + lane;
        int row = ch >> 4, off = ch & 15;
        if (r0 + row < n)
            *(ushort8v*)(KVb + (size_t)(r0 + row) * 128 + off * 8) =
                *(const ushort8v*)(kt + row * KV_STRIDE + off * 8);
    }
    #pragma unroll
    for (int k4 = 0; k4 < 4; ++k4) {            // S: 256 chunks of float4
        int ch = k4 * 64 + lane;
        int row = ch >> 4, off = ch & 15;
        if (r0 + row < n)
            *(float4*)(S + (size_t)(r0 + row) * 64 + off * 4) =
                *(const float4*)(st + row * ST_STRIDE + off * 4);
    }
}

// ---------------------------------------------------------------------------
// Fused attention aggregate: one 8-lane group per dst node, nodes visited in
// degree-sorted order (order[]) so a wave's 8 groups have equal trip counts.
// Per edge: 4B record broadcast, K+V halves of one 256B row, 8-wide dot + 3
// shuffles, exp per lane, shuffle-free accumulate. Unrolled x2.
// out = (sum p*V)/sum p + (sum p*ea)/sum p * We + S   (+relu, bf16 for L1).
// ---------------------------------------------------------------------------
template<int L1>
__global__ __launch_bounds__(256) void agg3_kernel(
    const ushort* __restrict__ Qb, const ushort* __restrict__ KVb,
    const float* __restrict__ S, const float* __restrict__ qWe,
    const float* __restrict__ We, const int* __restrict__ row_ptr,
    const uint* __restrict__ cse, const int* __restrict__ order,
    void* __restrict__ outp, int n, int E)
{
    int q8 = threadIdx.x & 7;
    int gid = (blockIdx.x * blockDim.x + threadIdx.x) >> 3;
    int ng  = (gridDim.x * blockDim.x) >> 3;
    float4 weA = ((const float4*)We)[2 * q8];
    float4 weB = ((const float4*)We)[2 * q8 + 1];

    for (int ii = gid; ii < n; ii += ng) {
        int i = clampi(order[ii], 0, n - 1);
        int beg = clampi(row_ptr[i], 0, E);
        int end = clampi(row_ptr[i + 1], beg, E);
        ushort8v q8v = *(const ushort8v*)(Qb + (size_t)i * 64 + 8 * q8);
        float4 qA = make_float4(bf2f(q8v[0]), bf2f(q8v[1]), bf2f(q8v[2]), bf2f(q8v[3]));
        float4 qB = make_float4(bf2f(q8v[4]), bf2f(q8v[5]), bf2f(q8v[6]), bf2f(q8v[7]));
        float qwe8 = qWe[i] * 0.125f;
        f32x4 aA = {0.f, 0.f, 0.f, 0.f}, aB = {0.f, 0.f, 0.f, 0.f};
        float ssum = 0.f, sea = 0.f;

        int e = beg;
        for (; e + 2 <= end; e += 2) {
            uint ed0 = cse[e], ed1 = cse[e + 1];
            const ushort* r0 = KVb + (size_t)clampi(rec_src(ed0), 0, n - 1) * 128 + 8 * q8;
            const ushort* r1 = KVb + (size_t)clampi(rec_src(ed1), 0, n - 1) * 128 + 8 * q8;
            ushort8v k0 = *(const ushort8v*)(r0);
            ushort8v v0 = *(const ushort8v*)(r0 + 64);
            ushort8v k1 = *(const ushort8v*)(r1);
            ushort8v v1 = *(const ushort8v*)(r1 + 64);
            float ea0 = rec_ea(ed0), ea1 = rec_ea(ed1);
            float d0 = dot8(qA, qB, k0);
            float d1 = dot8(qA, qB, k1);
            d0 += __shfl_xor(d0, 1); d1 += __shfl_xor(d1, 1);
            d0 += __shfl_xor(d0, 2); d1 += __shfl_xor(d1, 2);
            d0 += __shfl_xor(d0, 4); d1 += __shfl_xor(d1, 4);
            float p0 = __expf(fmaf(ea0, qwe8, d0 * 0.125f));
            float p1 = __expf(fmaf(ea1, qwe8, d1 * 0.125f));
            ssum += p0 + p1;
            sea = fmaf(p0, ea0, fmaf(p1, ea1, sea));
            aA[0] = fmaf(p0, bf2f(v0[0]), fmaf(p1, bf2f(v1[0]), aA[0]));
            aA[1] = fmaf(p0, bf2f(v0[1]), fmaf(p1, bf2f(v1[1]), aA[1]));
            aA[2] = fmaf(p0, bf2f(v0[2]), fmaf(p1, bf2f(v1[2]), aA[2]));
            aA[3] = fmaf(p0, bf2f(v0[3]), fmaf(p1, bf2f(v1[3]), aA[3]));
            aB[0] = fmaf(p0, bf2f(v0[4]), fmaf(p1, bf2f(v1[4]), aB[0]));
            aB[1] = fmaf(p0, bf2f(v0[5]), fmaf(p1, bf2f(v1[5]), aB[1]));
            aB[2] = fmaf(p0, bf2f(v0[6]), fmaf(p1, bf2f(v1[6]), aB[2]));
            aB[3] = fmaf(p0, bf2f(v0[7]), fmaf(p1, bf2f(v1[7]), aB[3]));
        }
        if (e < end) {
            uint ed = cse[e];
            const ushort* row = KVb + (size_t)clampi(rec_src(ed), 0, n - 1) * 128 + 8 * q8;
            ushort8v k0 = *(const ushort8v*)(row);
            ushort8v v0 = *(const ushort8v*)(row + 64);
            float ea0 = rec_ea(ed);
            float d0 = dot8(qA, qB, k0);
            d0 += __shfl_xor(d0, 1);
            d0 += __shfl_xor(d0, 2);
            d0 += __shfl_xor(d0, 4);
            float p0 = __expf(fmaf(ea0, qwe8, d0 * 0.125f));
            ssum += p0;
            sea = fmaf(p0, ea0, sea);
            aA[0] = fmaf(p0, bf2f(v0[0]), aA[0]);
            aA[1] = fmaf(p0, bf2f(v0[1]), aA[1]);
            aA[2] = fmaf(p0, bf2f(v0[2]), aA[2]);
            aA[3] = fmaf(p0, bf2f(v0[3]), aA[3]);
            aB[0] = fmaf(p0, bf2f(v0[4]), aB[0]);
            aB[1] = fmaf(p0, bf2f(v0[5]), aB[1]);
            aB[2] = fmaf(p0, bf2f(v0[6]), aB[2]);
            aB[3] = fmaf(p0, bf2f(v0[7]), aB[3]);
        }

        float inv = (ssum > 0.f) ? 1.f / ssum : 0.f;
        float eawe = sea * inv;
        const float4* Srow = (const float4*)(S + (size_t)i * 64);
        float4 sA = Srow[2 * q8], sB = Srow[2 * q8 + 1];
        float o0 = fmaf(aA[0], inv, fmaf(eawe, weA.x, sA.x));
        float o1 = fmaf(aA[1], inv, fmaf(eawe, weA.y, sA.y));
        float o2 = fmaf(aA[2], inv, fmaf(eawe, weA.z, sA.z));
        float o3 = fmaf(aA[3], inv, fmaf(eawe, weA.w, sA.w));
        float o4 = fmaf(aB[0], inv, fmaf(eawe, weB.x, sB.x));
        float o5 = fmaf(aB[1], inv, fmaf(eawe, weB.y, sB.y));
        float o6 = fmaf(aB[2], inv, fmaf(eawe, weB.z, sB.z));
        float o7 = fmaf(aB[3], inv, fmaf(eawe, weB.w, sB.w));
        if (L1) {
            o0 = fmaxf(o0, 0.f); o1 = fmaxf(o1, 0.f); o2 = fmaxf(o2, 0.f); o3 = fmaxf(o3, 0.f);
            o4 = fmaxf(o4, 0.f); o5 = fmaxf(o5, 0.f); o6 = fmaxf(o6, 0.f); o7 = fmaxf(o7, 0.f);
            union { ushort u[8]; ushort8v v; } ov;
            ov.u[0] = f2bf(o0); ov.u[1] = f2bf(o1); ov.u[2] = f2bf(o2); ov.u[3] = f2bf(o3);
            ov.u[4] = f2bf(o4); ov.u[5] = f2bf(o5); ov.u[6] = f2bf(o6); ov.u[7] = f2bf(o7);
            *(ushort8v*)((ushort*)outp + (size_t)i * 64 + 8 * q8) = ov.v;
        } else {
            float4* Or = (float4*)((float*)outp + (size_t)i * 64);
            Or[2 * q8]     = make_float4(o0, o1, o2, o3);
            Or[2 * q8 + 1] = make_float4(o4, o5, o6, o7);
        }
    }
}

// ---------------------------------------------------------------------------
extern "C" void kernel_launch(void* const* d_in, const int* in_sizes, int n_in,
                              void* d_out, int out_size, void* d_ws, size_t ws_size,
                              hipStream_t stream) {
    const float* x   = (const float*)d_in[0];
    const int*   ei  = (const int*)d_in[1];     // int32 on device
    const float* ea  = (const float*)d_in[2];
    const float *Wq1 = (const float*)d_in[3],  *bq1 = (const float*)d_in[4];
    const float *Wk1 = (const float*)d_in[5],  *bk1 = (const float*)d_in[6];
    const float *Wv1 = (const float*)d_in[7],  *bv1 = (const float*)d_in[8];
    const float *We1 = (const float*)d_in[9];
    const float *Ws1 = (const float*)d_in[10], *bs1 = (const float*)d_in[11];
    const float *Wq2 = (const float*)d_in[12], *bq2 = (const float*)d_in[13];
    const float *Wk2 = (const float*)d_in[14], *bk2 = (const float*)d_in[15];
    const float *Wv2 = (const float*)d_in[16], *bv2 = (const float*)d_in[17];
    const float *We2 = (const float*)d_in[18];
    const float *Ws2 = (const float*)d_in[19], *bs2 = (const float*)d_in[20];

    const int N_ = in_sizes[0] / 64;   // 50000
    const int E_ = in_sizes[2];        // 800000

    char* wsb = (char*)d_ws;
    size_t off = 0;
    auto carve = [&](size_t bytes) -> void* {
        void* p = (void*)(wsb + off);
        off += (bytes + 255) & ~(size_t)255;
        return p;
    };
    ushort* Qb   = (ushort*)carve((size_t)N_ * 64 * 2);
    float*  S    = (float*)carve((size_t)N_ * 64 * 4);
    ushort* KVb  = (ushort*)carve((size_t)N_ * 128 * 2);
    ushort* hb   = (ushort*)carve((size_t)N_ * 64 * 2);
    float*  qWe  = (float*)carve((size_t)N_ * 4);
    int*    count   = (int*)carve((size_t)N_ * 4);
    int*    row_ptr = (int*)carve((size_t)(N_ + 1) * 4);
    int*    rank    = (int*)carve((size_t)E_ * 4);
    uint*   cse     = (uint*)carve((size_t)E_ * 4);
    int*    nrank   = (int*)carve((size_t)N_ * 4);
    int*    order   = (int*)carve((size_t)N_ * 4);
    int*    dcount  = (int*)carve(64 * 4);
    int*    dbase   = (int*)carve(64 * 4);
    ushort* Bp1     = (ushort*)carve(2048 * 8 * 2);
    ushort* Bp2     = (ushort*)carve(2048 * 8 * 2);
    (void)ws_size; (void)n_in; (void)out_size;

    pack_and_zero<<<16 + (N_ + 255) / 256, 256, 0, stream>>>(
        Wq1, Wk1, Wv1, Ws1, Wq2, Wk2, Wv2, Ws2, Bp1, Bp2, count, dcount, N_);

    // CSR build (atomic-free scatter via hist ranks)
    hist_kernel<<<(E_ + 255) / 256, 256, 0, stream>>>(ei, count, rank, E_, N_);
    scan_exclusive<<<1, 1024, 0, stream>>>(count, row_ptr, N_);
    scatter_kernel<<<(E_ + 255) / 256, 256, 0, stream>>>(ei, ea, rank, row_ptr, cse, E_, N_);

    // Degree-sorted node order (two-level counting sort)
    deg_hist<<<(N_ + 255) / 256, 256, 0, stream>>>(row_ptr, dcount, nrank, N_);
    dscan_kernel<<<1, 64, 0, stream>>>(dcount, dbase);
    dscatter_kernel<<<(N_ + 255) / 256, 256, 0, stream>>>(row_ptr, dbase, nrank, order, N_);

    int ntb = (((N_ + 15) / 16) + 3) / 4;

    // Layer 1
    node_transform_mfma<true><<<ntb, 256, 0, stream>>>(x, Bp1, We1, bq1, bk1, bv1, bs1,
                                                       Qb, KVb, S, qWe, N_);
    agg3_kernel<1><<<1568, 256, 0, stream>>>(Qb, KVb, S, qWe, We1, row_ptr, cse, order,
                                             hb, N_, E_);
    // Layer 2
    node_transform_mfma<false><<<ntb, 256, 0, stream>>>(hb, Bp2, We2, bq2, bk2, bv2, bs2,
                                                        Qb, KVb, S, qWe, N_);
    agg3_kernel<0><<<1568, 256, 0, stream>>>(Qb, KVb, S, qWe, We2, row_ptr, cse, order,
                                             d_out, N_, E_);
}